// Round 5
// baseline (282.461 us; speedup 1.0000x reference)
//
#include <hip/hip_runtime.h>
#include <hip/hip_bf16.h>

// Problem constants (B=8192, D=128 from reference setup_inputs)
constexpr int Bh = 8192;
constexpr int Nn = 16384;   // 2*B
constexpr int Dd = 128;
constexpr float EPS = 1e-8f;
constexpr float LN2 = 0.69314718056f;

constexpr int TILE_COLS = 128;     // LDS-staged column tile
constexpr int K_TILES = 2;         // col-tiles per block
constexpr int N_TILES = 4160;      // upper-triangle 256x128 tiles
constexpr int N_BLOCKS = N_TILES / K_TILES;   // 2080, exact

typedef short bf16x8 __attribute__((ext_vector_type(8)));
typedef float f32x4 __attribute__((ext_vector_type(4)));

// ---- Kernel 1: fp32 -> bf16, scaled by sqrt(2*log2e) so MFMA dot == sim/tau*log2e ----
__global__ __launch_bounds__(256) void convert_kernel(const float4* __restrict__ za,
                                                      const float4* __restrict__ zb,
                                                      ushort* __restrict__ z,
                                                      float* __restrict__ rowsum) {
    const int t = blockIdx.x * 256 + threadIdx.x;        // 0 .. 524287
    constexpr int Q = (Bh * Dd) / 4;                     // 262144 float4 per input
    const float SCL = 1.69864363f;                       // sqrt(2 * 1.4426950409)
    float4 v = (t < Q) ? za[t] : zb[t - Q];
    union { ushort4 u4; __hip_bfloat16 h[4]; } cv;
    cv.h[0] = __float2bfloat16(v.x * SCL);
    cv.h[1] = __float2bfloat16(v.y * SCL);
    cv.h[2] = __float2bfloat16(v.z * SCL);
    cv.h[3] = __float2bfloat16(v.w * SCL);
    ((ushort4*)z)[t] = cv.u4;
    if (t < Nn) rowsum[t] = 0.f;
}

// tile index g -> row-block b: largest b with cum(b) = b*(129-b) <= g
__device__ __forceinline__ int row_block_of(int g) {
    int b = (int)((129.0f - sqrtf((float)(16641 - 4 * g))) * 0.5f);
    b = b < 0 ? 0 : (b > 63 ? 63 : b);
    while (b * (129 - b) > g) --b;
    while ((b + 1) * (128 - b) <= g) ++b;
    return b;
}

// row-credit flush: reduce rs over the 16 col-lanes, one atomic per row (log2 domain)
__device__ __forceinline__ void flush_rs(float* __restrict__ rowsum, int rowW,
                                         float (&rs)[2][4], int q, int c) {
#pragma unroll
    for (int s = 0; s < 2; ++s)
#pragma unroll
        for (int r = 0; r < 4; ++r) {
            float v = rs[s][r];
            v += __shfl_xor(v, 1);
            v += __shfl_xor(v, 2);
            v += __shfl_xor(v, 4);
            v += __shfl_xor(v, 8);
            if (c == 0) atomicAdd(&rowsum[rowW + s * 16 + q * 4 + r], v);
            rs[s][r] = 0.f;
        }
}

// ---- Kernel 2: symmetric upper-triangle, 512 threads (8 waves x 32 rows),
// double-buffered swizzled LDS, one barrier per tile, register prefetch. ----
__global__ __launch_bounds__(512, 4) void main_kernel(const ushort* __restrict__ z,
                                                      float* __restrict__ rowsum,
                                                      float* __restrict__ pospair) {
    // Two 128x128 bf16 buffers, stride 128 (XOR swizzle: chunk ci of col at ci^(col&15)).
    // Same 2-way bank profile as +8 padding but fits 2 buffers in exactly 64 KB.
    __shared__ ushort lds[2][TILE_COLS * 128];   // 65536 B

    const int tid = threadIdx.x;
    const int wave = tid >> 6;
    const int lane = tid & 63;
    const int q = lane >> 4;        // quad: 0..3
    const int c = lane & 15;        // 0..15
    const int g0 = blockIdx.x * K_TILES;

    int bb[K_TILES], cc[K_TILES];
#pragma unroll
    for (int j = 0; j < K_TILES; ++j) {
        int g = g0 + j;
        int b = row_block_of(g);
        bb[j] = b;
        cc[j] = 2 * b + (g - b * (129 - b));
    }

    // staging: 2048 16B-chunks / 512 threads = 4 each; swizzled LDS offsets
    int goff[4], loff[4];
#pragma unroll
    for (int it = 0; it < 4; ++it) {
        int chunk = it * 512 + tid;
        int ccol = chunk >> 4;
        int ci = chunk & 15;
        goff[it] = chunk * 8;                                 // element offset in tile
        loff[it] = ccol * 128 + ((ci ^ (ccol & 15)) << 3);    // swizzled element offset
    }

    // prologue: stage tile 0 into buffer 0
    uint4 pf[4];
    {
        const ushort* src = z + ((size_t)cc[0] << 14);        // cc[0]*128 cols * 128 k
#pragma unroll
        for (int it = 0; it < 4; ++it) pf[it] = *(const uint4*)(src + goff[it]);
#pragma unroll
        for (int it = 0; it < 4; ++it) *(uint4*)(&lds[0][loff[it]]) = pf[it];
    }

    // A fragments: 2 row-sets x 4 k-tiles (32 VGPRs)
    bf16x8 afrag[2][4];
    int cur_b = bb[0];
    int rowW = (cur_b << 8) + wave * 32;
#pragma unroll
    for (int s = 0; s < 2; ++s) {
        const ushort* ap = z + (size_t)(rowW + s * 16 + c) * Dd;
#pragma unroll
        for (int kt = 0; kt < 4; ++kt)
            afrag[s][kt] = *(const bf16x8*)(ap + kt * 32 + q * 8);
    }

    float rs[2][4];
    float csum[8];
#pragma unroll
    for (int s = 0; s < 2; ++s)
#pragma unroll
        for (int r = 0; r < 4; ++r) rs[s][r] = 0.f;
#pragma unroll
    for (int st = 0; st < 8; ++st) csum[st] = 0.f;

    __syncthreads();

    for (int j = 0; j < K_TILES; ++j) {
        const int ct = cc[j];
        const int C0 = ct << 7;
        const ushort* buf = lds[j & 1];

        if (j + 1 < K_TILES) {   // prefetch next tile into registers (overlaps compute)
            const ushort* src = z + ((size_t)cc[j + 1] << 14);
#pragma unroll
            for (int it = 0; it < 4; ++it) pf[it] = *(const uint4*)(src + goff[it]);
        }

        const int rt = rowW >> 7;             // this wave's 128-row tile
        const bool skip = (ct < rt);          // below diagonal: mirror covers it
        const bool diag = (ct == rt);
        if (!skip) {
#pragma unroll
            for (int st = 0; st < 8; ++st) {
                f32x4 acc[2] = {{0.f,0.f,0.f,0.f},{0.f,0.f,0.f,0.f}};
#pragma unroll
                for (int kt = 0; kt < 4; ++kt) {
                    bf16x8 bfrag = *(const bf16x8*)(&buf[(st * 16 + c) * 128 + ((((kt << 2) | q) ^ c) << 3)]);
                    acc[0] = __builtin_amdgcn_mfma_f32_16x16x32_bf16(afrag[0][kt], bfrag, acc[0], 0, 0, 0);
                    acc[1] = __builtin_amdgcn_mfma_f32_16x16x32_bf16(afrag[1][kt], bfrag, acc[1], 0, 0, 0);
                }
                const int gc0 = C0 + st * 16;
#pragma unroll
                for (int s = 0; s < 2; ++s) {
                    const int R = rowW + s * 16;
                    float sp[4];
#pragma unroll
                    for (int r = 0; r < 4; ++r) {
                        float u = acc[s][r];
                        // softplus in log2 domain: max(u,0) + log2(1 + 2^-|u|)
                        float e = __builtin_amdgcn_exp2f(-fabsf(u));
                        sp[r] = fmaxf(u, 0.f) + __builtin_amdgcn_logf(1.f + e);
                    }
                    if (diag && gc0 == R) {               // zero self-similarity
#pragma unroll
                        for (int r = 0; r < 4; ++r)
                            if (c == q * 4 + r) sp[r] = 0.f;
                    }
                    if (gc0 == (R ^ Bh)) {                // positive-pair subtile (rows<8192)
#pragma unroll
                        for (int r = 0; r < 4; ++r)
                            if (c == q * 4 + r) pospair[R + q * 4 + r] = sp[r];
                    }
#pragma unroll
                    for (int r = 0; r < 4; ++r) rs[s][r] += sp[r];
                    if (!diag) csum[st] += (sp[0] + sp[1]) + (sp[2] + sp[3]);
                }
            }
            if (!diag) {   // col credit: reduce over q, one atomic per col
#pragma unroll
                for (int st = 0; st < 8; ++st) {
                    float v = csum[st];
                    v += __shfl_xor(v, 16);
                    v += __shfl_xor(v, 32);
                    if (lane < 16) atomicAdd(&rowsum[C0 + st * 16 + c], v);
                    csum[st] = 0.f;
                }
            }
        }

        if (j + 1 < K_TILES) {
            ushort* dst = (ushort*)lds[(j + 1) & 1];
#pragma unroll
            for (int it = 0; it < 4; ++it) *(uint4*)(&dst[loff[it]]) = pf[it];
            if (bb[j + 1] != cur_b) {     // row-block changes (rare: ~64/2080 blocks)
                flush_rs(rowsum, rowW, rs, q, c);
                cur_b = bb[j + 1];
                rowW = (cur_b << 8) + wave * 32;
#pragma unroll
                for (int s = 0; s < 2; ++s) {
                    const ushort* ap = z + (size_t)(rowW + s * 16 + c) * Dd;
#pragma unroll
                    for (int kt = 0; kt < 4; ++kt)
                        afrag[s][kt] = *(const bf16x8*)(ap + kt * 32 + q * 8);
                }
            }
            __syncthreads();   // single barrier per tile: dbuf write visible to all
        }
    }
    flush_rs(rowsum, rowW, rs, q, c);
}

// ---- Kernel 3: final loss (log2-domain sums back via ln2), 1024 threads ----
__global__ __launch_bounds__(1024) void finalize_kernel(const float* __restrict__ rowsum,
                                                        const float* __restrict__ pospair,
                                                        float* __restrict__ out) {
    __shared__ float red[16];
    float acc = 0.f;
    for (int i = threadIdx.x; i < Nn; i += 1024) {
        float denom = fmaxf(LN2 * rowsum[i], EPS);
        float sp = fmaxf(LN2 * pospair[i & (Bh - 1)], EPS);   // pospair[i]==pospair[i^B]
        acc += __logf(sp) - __logf(denom);
    }
#pragma unroll
    for (int m = 1; m < 64; m <<= 1) acc += __shfl_xor(acc, m);
    if ((threadIdx.x & 63) == 0) red[threadIdx.x >> 6] = acc;
    __syncthreads();
    if (threadIdx.x < 16) {
        float v = red[threadIdx.x];
        v += __shfl_xor(v, 1);
        v += __shfl_xor(v, 2);
        v += __shfl_xor(v, 4);
        v += __shfl_xor(v, 8);
        if (threadIdx.x == 0) out[0] = -v / (float)Nn;
    }
}

extern "C" void kernel_launch(void* const* d_in, const int* in_sizes, int n_in,
                              void* d_out, int out_size, void* d_ws, size_t ws_size,
                              hipStream_t stream) {
    const float* za = (const float*)d_in[0];
    const float* zb = (const float*)d_in[1];

    // workspace layout: z_bf16 (4 MB) | rowsum (64 KB) | pospair (32 KB used)
    ushort* z = (ushort*)d_ws;
    float* rowsum = (float*)((char*)d_ws + (size_t)Nn * Dd * 2);
    float* pospair = rowsum + Nn;
    float* out = (float*)d_out;

    convert_kernel<<<2048, 256, 0, stream>>>((const float4*)za, (const float4*)zb, z, rowsum);
    main_kernel<<<N_BLOCKS, 512, 0, stream>>>(z, rowsum, pospair);
    finalize_kernel<<<1, 1024, 0, stream>>>(rowsum, pospair, out);
}

// Round 6
// 209.356 us; speedup vs baseline: 1.3492x; 1.3492x over previous
//
#include <hip/hip_runtime.h>
#include <hip/hip_bf16.h>

// Problem constants (B=8192, D=128 from reference setup_inputs)
constexpr int Bh = 8192;
constexpr int Nn = 16384;   // 2*B
constexpr int Dd = 128;
constexpr float EPS = 1e-8f;
constexpr float LN2 = 0.69314718056f;

constexpr int K_TILES = 4;         // col-tiles per block
constexpr int N_TILES = 4160;      // upper-triangle 256x128 tiles
constexpr int N_BLOCKS = N_TILES / K_TILES;   // 1040, exact

typedef short bf16x8 __attribute__((ext_vector_type(8)));
typedef float f32x4 __attribute__((ext_vector_type(4)));

// ---- Kernel 1: fp32 -> bf16, scaled by sqrt(2*log2e) so MFMA dot == sim/tau*log2e ----
__global__ __launch_bounds__(256) void convert_kernel(const float4* __restrict__ za,
                                                      const float4* __restrict__ zb,
                                                      ushort* __restrict__ z,
                                                      float* __restrict__ rowsum) {
    const int t = blockIdx.x * 256 + threadIdx.x;        // 0 .. 524287
    constexpr int Q = (Bh * Dd) / 4;                     // 262144 float4 per input
    const float SCL = 1.69864363f;                       // sqrt(2 * 1.4426950409)
    float4 v = (t < Q) ? za[t] : zb[t - Q];
    union { ushort4 u4; __hip_bfloat16 h[4]; } cv;
    cv.h[0] = __float2bfloat16(v.x * SCL);
    cv.h[1] = __float2bfloat16(v.y * SCL);
    cv.h[2] = __float2bfloat16(v.z * SCL);
    cv.h[3] = __float2bfloat16(v.w * SCL);
    ((ushort4*)z)[t] = cv.u4;
    if (t < Nn) rowsum[t] = 0.f;
}

// tile index g -> row-block b: largest b with cum(b) = b*(129-b) <= g
__device__ __forceinline__ int row_block_of(int g) {
    int b = (int)((129.0f - sqrtf((float)(16641 - 4 * g))) * 0.5f);
    b = b < 0 ? 0 : (b > 63 ? 63 : b);
    while (b * (129 - b) > g) --b;
    while ((b + 1) * (128 - b) <= g) ++b;
    return b;
}

// row-credit flush: reduce rs over the 16 col-lanes, one atomic per row (log2 domain)
__device__ __forceinline__ void flush_rs(float* __restrict__ rowsum, int rowW,
                                         float (&rs)[4][4], int q, int c) {
#pragma unroll
    for (int s = 0; s < 4; ++s)
#pragma unroll
        for (int r = 0; r < 4; ++r) {
            float v = rs[s][r];
            v += __shfl_xor(v, 1);
            v += __shfl_xor(v, 2);
            v += __shfl_xor(v, 4);
            v += __shfl_xor(v, 8);
            if (c == 0) atomicAdd(&rowsum[rowW + s * 16 + q * 4 + r], v);
            rs[s][r] = 0.f;
        }
}

// ---- Kernel 2: symmetric upper-triangle, NO LDS / NO BARRIERS.
// z is 4 MB -> fully L2-resident; a wave's B-tile slice is 32 KB (L1-sized).
// Each wave streams B-fragments straight from global with dwordx4 loads
// (per instr: 16 cols x 64 B contiguous = fully coalesced), double-buffered
// in registers so the next st's 4 loads are in flight during this st's
// softplus epilogue. Waves are fully independent -> no barrier stalls
// (R4's stage/barrier structure idled ~60% of cycles).
// NOTE: plain __launch_bounds__(256) — a min-waves arg (R1: (256,4), R5:
// (512,4)) clamps VGPRs to 64 and spills ~0.5-2 GB to scratch. Never again.
__global__ __launch_bounds__(256) void main_kernel(const ushort* __restrict__ z,
                                                   float* __restrict__ rowsum,
                                                   float* __restrict__ pospair) {
    const int tid = threadIdx.x;
    const int wave = tid >> 6;
    const int lane = tid & 63;
    const int q = lane >> 4;        // quad: 0..3
    const int c = lane & 15;        // 0..15
    const int g0 = blockIdx.x * K_TILES;

    bf16x8 afrag[4][4];
    float rs[4][4];
    float csum[8];
    int cur_b = -1;
    int rowW = 0;

#pragma unroll
    for (int s = 0; s < 4; ++s)
#pragma unroll
        for (int r = 0; r < 4; ++r) rs[s][r] = 0.f;
#pragma unroll
    for (int st = 0; st < 8; ++st) csum[st] = 0.f;

    for (int j = 0; j < K_TILES; ++j) {
        const int g = g0 + j;
        int b = row_block_of(g);
        const int ct = 2 * b + (g - b * (129 - b));
        const int C0 = ct << 7;

        if (b != cur_b) {
            if (cur_b >= 0) flush_rs(rowsum, rowW, rs, q, c);
            cur_b = b;
            rowW = (b << 8) + wave * 64;
#pragma unroll
            for (int s = 0; s < 4; ++s) {
                const ushort* ap = z + (size_t)(rowW + s * 16 + c) * Dd;
#pragma unroll
                for (int kt = 0; kt < 4; ++kt)
                    afrag[s][kt] = *(const bf16x8*)(ap + kt * 32 + q * 8);
            }
        }

        const int rt = rowW >> 7;             // this wave's 128-row tile
        const bool skip = (ct < rt);          // below diagonal: mirror covers it
        const bool diag = (ct == rt);
        if (skip) continue;

        // per-lane B base: col = C0 + c, k-offset q*8; bfrag(st,kt) at +st*2048 + kt*32
        const ushort* bp = z + ((size_t)(C0 + c) << 7) + (q << 3);

        bf16x8 bcur[4], bnxt[4];
#pragma unroll
        for (int kt = 0; kt < 4; ++kt) bcur[kt] = *(const bf16x8*)(bp + kt * 32);

#pragma unroll
        for (int st = 0; st < 8; ++st) {
            if (st < 7) {     // prefetch next st's B while this st computes
#pragma unroll
                for (int kt = 0; kt < 4; ++kt)
                    bnxt[kt] = *(const bf16x8*)(bp + (st + 1) * 2048 + kt * 32);
            }
            f32x4 acc[4] = {{0.f,0.f,0.f,0.f},{0.f,0.f,0.f,0.f},{0.f,0.f,0.f,0.f},{0.f,0.f,0.f,0.f}};
#pragma unroll
            for (int kt = 0; kt < 4; ++kt) {
#pragma unroll
                for (int s = 0; s < 4; ++s)
                    acc[s] = __builtin_amdgcn_mfma_f32_16x16x32_bf16(afrag[s][kt], bcur[kt], acc[s], 0, 0, 0);
            }
            const int gc0 = C0 + st * 16;
#pragma unroll
            for (int s = 0; s < 4; ++s) {
                const int R = rowW + s * 16;
                float sp[4];
#pragma unroll
                for (int r = 0; r < 4; ++r) {
                    float u = acc[s][r];
                    // softplus in log2 domain: max(u,0) + log2(1 + 2^-|u|)
                    float e = __builtin_amdgcn_exp2f(-fabsf(u));
                    sp[r] = fmaxf(u, 0.f) + __builtin_amdgcn_logf(1.f + e);
                }
                if (diag && gc0 == R) {               // zero self-similarity
#pragma unroll
                    for (int r = 0; r < 4; ++r)
                        if (c == q * 4 + r) sp[r] = 0.f;
                }
                if (gc0 == (R ^ Bh)) {                // positive-pair subtile (rows<8192)
#pragma unroll
                    for (int r = 0; r < 4; ++r)
                        if (c == q * 4 + r) pospair[R + q * 4 + r] = sp[r];
                }
#pragma unroll
                for (int r = 0; r < 4; ++r) rs[s][r] += sp[r];
                if (!diag) csum[st] += (sp[0] + sp[1]) + (sp[2] + sp[3]);
            }
#pragma unroll
            for (int kt = 0; kt < 4; ++kt) bcur[kt] = bnxt[kt];
        }
        if (!diag) {   // col credit: reduce over q (rows), one atomic per col
#pragma unroll
            for (int st = 0; st < 8; ++st) {
                float v = csum[st];
                v += __shfl_xor(v, 16);
                v += __shfl_xor(v, 32);
                if (lane < 16) atomicAdd(&rowsum[C0 + st * 16 + c], v);
                csum[st] = 0.f;
            }
        }
    }
    if (cur_b >= 0) flush_rs(rowsum, rowW, rs, q, c);
}

// ---- Kernel 3: final loss (log2-domain sums back via ln2), 1024 threads ----
__global__ __launch_bounds__(1024) void finalize_kernel(const float* __restrict__ rowsum,
                                                        const float* __restrict__ pospair,
                                                        float* __restrict__ out) {
    __shared__ float red[16];
    float acc = 0.f;
    for (int i = threadIdx.x; i < Nn; i += 1024) {
        float denom = fmaxf(LN2 * rowsum[i], EPS);
        float sp = fmaxf(LN2 * pospair[i & (Bh - 1)], EPS);   // pospair[i]==pospair[i^B]
        acc += __logf(sp) - __logf(denom);
    }
#pragma unroll
    for (int m = 1; m < 64; m <<= 1) acc += __shfl_xor(acc, m);
    if ((threadIdx.x & 63) == 0) red[threadIdx.x >> 6] = acc;
    __syncthreads();
    if (threadIdx.x < 16) {
        float v = red[threadIdx.x];
        v += __shfl_xor(v, 1);
        v += __shfl_xor(v, 2);
        v += __shfl_xor(v, 4);
        v += __shfl_xor(v, 8);
        if (threadIdx.x == 0) out[0] = -v / (float)Nn;
    }
}

extern "C" void kernel_launch(void* const* d_in, const int* in_sizes, int n_in,
                              void* d_out, int out_size, void* d_ws, size_t ws_size,
                              hipStream_t stream) {
    const float* za = (const float*)d_in[0];
    const float* zb = (const float*)d_in[1];

    // workspace layout: z_bf16 (4 MB) | rowsum (64 KB) | pospair (32 KB used)
    ushort* z = (ushort*)d_ws;
    float* rowsum = (float*)((char*)d_ws + (size_t)Nn * Dd * 2);
    float* pospair = rowsum + Nn;
    float* out = (float*)d_out;

    convert_kernel<<<2048, 256, 0, stream>>>((const float4*)za, (const float4*)zb, z, rowsum);
    main_kernel<<<N_BLOCKS, 256, 0, stream>>>(z, rowsum, pospair);
    finalize_kernel<<<1, 1024, 0, stream>>>(rowsum, pospair, out);
}